// Round 1
// baseline (1494.659 us; speedup 1.0000x reference)
//
#include <hip/hip_runtime.h>
#include <math.h>

// Problem constants (fixed by setup_inputs).
#define TT 16384
#define HH 4096
#define EE 256

// GEMM tiling: BN = EE = 256 (full expert dim per block -> x read once).
#define BM 32
#define BK 32

// ---------------------------------------------------------------------------
// CAS-based double atomic add (no dependence on -munsafe-fp-atomics).
__device__ inline void atom_add_double(double* addr, double val) {
    unsigned long long* p = (unsigned long long*)addr;
    unsigned long long old = *p, assumed;
    do {
        assumed = old;
        double nv = __longlong_as_double(assumed) + val;
        old = atomicCAS(p, assumed, __double_as_longlong(nv));
    } while (old != assumed);
}

__global__ __launch_bounds__(64) void zero_ws_kernel(double* z) {
    if (threadIdx.x == 0) *z = 0.0;
}

// ---------------------------------------------------------------------------
// Fused fp32 GEMM (raw = x @ W^T) + sigmoid + z-loss partial reduction.
// Block: 256 threads. Tile: BM x 256 output, BK k-slab.
// Per-thread tile: 4 rows x 8 cols. LDS padded +1 -> all accesses <=2-way.
__global__ __launch_bounds__(256) void gemm_sigmoid_kernel(
    const float* __restrict__ x,      // (TT, HH) row-major
    const float* __restrict__ w,      // (EE, HH) row-major
    float* __restrict__ logits,       // (TT, EE)
    double* __restrict__ zacc)
{
    __shared__ float As[BM][BK + 1];
    __shared__ float Bs[EE][BK + 1];
    __shared__ float zred[256];

    const int tid  = threadIdx.x;
    const int row0 = blockIdx.x * BM;
    const int ty   = tid >> 5;          // 0..7  -> rows ty*4 .. ty*4+3
    const int tx   = tid & 31;          // 0..31 -> cols tx + 32j
    const int lrow = tid >> 3;          // 0..31 (loader row)
    const int lk   = (tid & 7) << 2;    // 0,4,...,28 (loader k, float4)

    float acc[4][8];
#pragma unroll
    for (int i = 0; i < 4; ++i)
#pragma unroll
        for (int j = 0; j < 8; ++j) acc[i][j] = 0.f;

    for (int k0 = 0; k0 < HH; k0 += BK) {
        // Stage x tile: 32x32, one float4 per thread, coalesced along k.
        float4 xa = *(const float4*)(x + (size_t)(row0 + lrow) * HH + k0 + lk);
        As[lrow][lk + 0] = xa.x;
        As[lrow][lk + 1] = xa.y;
        As[lrow][lk + 2] = xa.z;
        As[lrow][lk + 3] = xa.w;
        // Stage W tile: 256x32, eight float4 per thread.
#pragma unroll
        for (int j = 0; j < 8; ++j) {
            const int e = lrow + (j << 5);
            float4 wb = *(const float4*)(w + (size_t)e * HH + k0 + lk);
            Bs[e][lk + 0] = wb.x;
            Bs[e][lk + 1] = wb.y;
            Bs[e][lk + 2] = wb.z;
            Bs[e][lk + 3] = wb.w;
        }
        __syncthreads();

#pragma unroll 8
        for (int kk = 0; kk < BK; ++kk) {
            float a[4], b[8];
#pragma unroll
            for (int i = 0; i < 4; ++i) a[i] = As[ty * 4 + i][kk];     // broadcast
#pragma unroll
            for (int j = 0; j < 8; ++j) b[j] = Bs[tx + (j << 5)][kk];  // 32 banks
#pragma unroll
            for (int i = 0; i < 4; ++i)
#pragma unroll
                for (int j = 0; j < 8; ++j)
                    acc[i][j] = fmaf(a[i], b[j], acc[i][j]);
        }
        __syncthreads();
    }

    // Epilogue: z-loss partial + sigmoid + store logits (coalesced across tx).
    float zs = 0.f;
#pragma unroll
    for (int i = 0; i < 4; ++i) {
        const int r = row0 + ty * 4 + i;
#pragma unroll
        for (int j = 0; j < 8; ++j) {
            const float v = acc[i][j];
            zs = fmaf(v, v, zs);
            logits[(size_t)r * EE + tx + (j << 5)] = 1.f / (1.f + expf(-v));
        }
    }
    zred[tid] = zs;
    __syncthreads();
    for (int s = 128; s > 0; s >>= 1) {
        if (tid < s) zred[tid] += zred[tid + s];
        __syncthreads();
    }
    if (tid == 0) atom_add_double(zacc, (double)zred[0]);
}

__global__ __launch_bounds__(64) void finalize_z_kernel(const double* zacc,
                                                        float* zout) {
    if (threadIdx.x == 0)
        *zout = (float)(*zacc / (double)((size_t)TT * (size_t)EE));
}

// ---------------------------------------------------------------------------
// Router: one wave (64 lanes) per token; lane l owns experts 4l..4l+3.
// Matches jax.lax.top_k stability: ties broken toward the LOWER index.
__global__ __launch_bounds__(256) void router_kernel(
    const float* __restrict__ logits,   // (TT, EE) sigmoid scores
    const float* __restrict__ bias,     // (EE)
    float* __restrict__ wout,           // (TT, 8)
    float* __restrict__ iout)           // (TT, 8) indices stored as float
{
    const int lane = threadIdx.x & 63;
    const int wv   = threadIdx.x >> 6;
    const int t    = blockIdx.x * 4 + wv;

    // logits region of d_out is only 4B-aligned -> scalar loads.
    const float* lrow = logits + (size_t)t * EE + lane * 4;
    float lg[4];
#pragma unroll
    for (int q = 0; q < 4; ++q) lg[q] = lrow[q];
    const float4 b4 = *(const float4*)(bias + lane * 4);
    const float bb[4] = {b4.x, b4.y, b4.z, b4.w};

    float sel[4];
#pragma unroll
    for (int q = 0; q < 4; ++q) sel[q] = lg[q] + bb[q];

    // ---- group score: sum of top-2 of the 32 experts in this lane's group.
    float m1 = sel[0], m2 = -INFINITY;
#pragma unroll
    for (int q = 1; q < 4; ++q) {
        if (sel[q] > m1) { m2 = m1; m1 = sel[q]; }
        else             { m2 = fmaxf(m2, sel[q]); }
    }
    // merge top-2 pairs across the 8 lanes of the group (lanes 8g..8g+7)
#pragma unroll
    for (int d = 1; d < 8; d <<= 1) {
        const float o1 = __shfl_xor(m1, d);
        const float o2 = __shfl_xor(m2, d);
        const float nm1 = fmaxf(m1, o1);
        const float nm2 = fmaxf(fminf(m1, o1), fmaxf(m2, o2));
        m1 = nm1; m2 = nm2;
    }
    const float gs = m1 + m2;
    const int g = lane >> 3;

    // ---- stable rank of this group's score among the 8 groups.
    int rank = 0;
#pragma unroll
    for (int gp = 0; gp < 8; ++gp) {
        const float og = __shfl(gs, gp << 3);
        rank += (og > gs) || (og == gs && gp < g);
    }
    const bool keep = rank < 4;  // TOPK_GROUP = 4

    float ms[4];
#pragma unroll
    for (int q = 0; q < 4; ++q)
        ms[q] = keep ? sel[q] : -3.402823466e38f;  // finfo(f32).min

    // ---- iterative top-8 with (value desc, index asc) wave argmax.
    float wvals[8];
    int   widx[8];
#pragma unroll
    for (int it = 0; it < 8; ++it) {
        float bv = ms[0];
        int bq = 0;
#pragma unroll
        for (int q = 1; q < 4; ++q)
            if (ms[q] > bv) { bv = ms[q]; bq = q; }   // strict > keeps low q
        int   bi = (lane << 2) + bq;
        float bl = lg[bq];
#pragma unroll
        for (int d = 1; d < 64; d <<= 1) {
            const float ov = __shfl_xor(bv, d);
            const int   oi = __shfl_xor(bi, d);
            const float ol = __shfl_xor(bl, d);
            if (ov > bv || (ov == bv && oi < bi)) { bv = ov; bi = oi; bl = ol; }
        }
        wvals[it] = bl;   // combine weight = raw sigmoid (bias-free)
        widx[it]  = bi;
        if ((bi >> 2) == lane) ms[bi & 3] = -INFINITY;  // owner invalidates
    }

    float s = 0.f;
#pragma unroll
    for (int it = 0; it < 8; ++it) s += wvals[it];
    s = fmaxf(s, 1e-9f);

    if (lane == 0) {
#pragma unroll
        for (int it = 0; it < 8; ++it) {
            wout[(size_t)t * 8 + it] = wvals[it] / s;
            iout[(size_t)t * 8 + it] = (float)widx[it];
        }
    }
}

// ---------------------------------------------------------------------------
extern "C" void kernel_launch(void* const* d_in, const int* in_sizes, int n_in,
                              void* d_out, int out_size, void* d_ws, size_t ws_size,
                              hipStream_t stream) {
    const float* x    = (const float*)d_in[0];   // (TT, HH)
    const float* w    = (const float*)d_in[1];   // (EE, HH)
    const float* bias = (const float*)d_in[2];   // (EE)

    float* out    = (float*)d_out;
    float* wout   = out;                      // weights: TT*8
    float* iout   = out + (size_t)TT * 8;     // indices (as float): TT*8
    float* zout   = out + (size_t)TT * 16;    // z_loss: 1
    float* logits = zout + 1;                 // logits: TT*EE
    double* zacc  = (double*)d_ws;

    zero_ws_kernel<<<1, 64, 0, stream>>>(zacc);
    gemm_sigmoid_kernel<<<TT / BM, 256, 0, stream>>>(x, w, logits, zacc);
    finalize_z_kernel<<<1, 64, 0, stream>>>(zacc, zout);
    router_kernel<<<TT / 4, 256, 0, stream>>>(logits, bias, wout, iout);
}